// Round 2
// baseline (665.027 us; speedup 1.0000x reference)
//
#include <hip/hip_runtime.h>
#include <math.h>

// ---------------------------------------------------------------------------
// 2-layer GCN on MI355X.
// NOTE: harness delivers integer inputs as int32 (edge_index: const int*,
// laid out [2][E] flat: first E = sources(row), next E = targets(col)).
// Pipeline per launch (graph-capture safe, no statics):
//   1. memset cnt; histogram of edge targets (int atomics)
//   2. exclusive scan -> CSR offsets (3-kernel scan)
//   3. finalize: offsets += block bases, cursor = offsets, dinv = 1/sqrt(deg+1)
//   4. fill CSR row-index array (atomic cursor)
//   5. h1s = dinv .* (x @ W1)                      [f32 reg-tiled GEMM]
//   6. a1  = relu(dinv[col]*(sum_nbr h1s + h1s[col]) + b1)   [pull gather]
//   7. h2s = dinv .* (a1 @ W2)
//   8. out = dinv[col]*(sum_nbr h2s + h2s[col]) + b2
// ---------------------------------------------------------------------------

__global__ void hist_kernel(const int* __restrict__ ei, int E,
                            int* __restrict__ cnt, int N) {
  int e = blockIdx.x * blockDim.x + threadIdx.x;
  if (e < E) {
    int c = ei[(size_t)E + e];  // col = target
    if ((unsigned)c < (unsigned)N) atomicAdd(&cnt[c], 1);
  }
}

__global__ __launch_bounds__(256) void scan_partial(const int* __restrict__ cnt,
                                                    int* __restrict__ offs,
                                                    int* __restrict__ bsums,
                                                    int N) {
  __shared__ int s[256];
  int t = threadIdx.x;
  int base = blockIdx.x * 1024 + t * 4;
  int v0 = (base + 0 < N) ? cnt[base + 0] : 0;
  int v1 = (base + 1 < N) ? cnt[base + 1] : 0;
  int v2 = (base + 2 < N) ? cnt[base + 2] : 0;
  int v3 = (base + 3 < N) ? cnt[base + 3] : 0;
  int sum = v0 + v1 + v2 + v3;
  s[t] = sum;
  __syncthreads();
#pragma unroll
  for (int d = 1; d < 256; d <<= 1) {
    int x = (t >= d) ? s[t - d] : 0;
    __syncthreads();
    s[t] += x;
    __syncthreads();
  }
  int excl = s[t] - sum;  // exclusive over thread sums within block
  if (base + 0 < N) offs[base + 0] = excl;
  if (base + 1 < N) offs[base + 1] = excl + v0;
  if (base + 2 < N) offs[base + 2] = excl + v0 + v1;
  if (base + 3 < N) offs[base + 3] = excl + v0 + v1 + v2;
  if (t == 255) bsums[blockIdx.x] = s[255];
}

__global__ __launch_bounds__(256) void scan_bsums(int* __restrict__ bsums, int nb) {
  // nb <= 256 (N=100K -> nb=98)
  __shared__ int s[256];
  int t = threadIdx.x;
  int v = (t < nb) ? bsums[t] : 0;
  s[t] = v;
  __syncthreads();
#pragma unroll
  for (int d = 1; d < 256; d <<= 1) {
    int x = (t >= d) ? s[t - d] : 0;
    __syncthreads();
    s[t] += x;
    __syncthreads();
  }
  if (t < nb) bsums[t] = s[t] - v;  // exclusive
}

__global__ void finalize_kernel(const int* __restrict__ cnt, int* __restrict__ offs,
                                int* __restrict__ cursor, float* __restrict__ dinv,
                                const int* __restrict__ bsums, int N, int E) {
  int i = blockIdx.x * blockDim.x + threadIdx.x;
  if (i < N) {
    int o = offs[i] + bsums[i >> 10];
    offs[i] = o;
    cursor[i] = o;
    dinv[i] = 1.0f / sqrtf((float)cnt[i] + 1.0f);  // deg includes self-loop
    if (i == 0) offs[N] = E;
  }
}

__global__ void fill_kernel(const int* __restrict__ ei, int E,
                            int* __restrict__ cursor, int* __restrict__ csr, int N) {
  int e = blockIdx.x * blockDim.x + threadIdx.x;
  if (e < E) {
    int r = ei[e];                 // row = source
    int c = ei[(size_t)E + e];     // col = target
    if ((unsigned)r < (unsigned)N && (unsigned)c < (unsigned)N) {
      int p = atomicAdd(&cursor[c], 1);
      if ((unsigned)p < (unsigned)E) csr[p] = r;
    }
  }
}

// out[n][c] = dinv[n] * sum_k A[n][k] * W[k][c]
// Register tile 4 rows x 8 cols per thread; K chunked by 64 through LDS.
template <int K, int NC, int RB>
__global__ __launch_bounds__(256) void gemm_scaled(const float* __restrict__ A,
                                                   const float* __restrict__ W,
                                                   const float* __restrict__ dinv,
                                                   float* __restrict__ out, int N) {
  constexpr int KC = 64;
  constexpr int TX = NC / 8;   // col groups
  constexpr int TY = RB / 4;   // row groups
  static_assert(TX * TY == 256, "bad tile");
  static_assert(K % KC == 0, "bad K");
  __shared__ float wl[KC * NC];
  __shared__ float xl[RB][KC + 1];   // +1 pad: conflict-free column reads

  int t = threadIdx.x;
  int tx = t % TX, ty = t / TX;
  int c0 = tx * 8;
  int r0 = blockIdx.x * RB;

  float acc[4][8];
#pragma unroll
  for (int r = 0; r < 4; ++r)
#pragma unroll
    for (int c = 0; c < 8; ++c) acc[r][c] = 0.f;

  for (int k0 = 0; k0 < K; k0 += KC) {
    __syncthreads();
    {  // stage W chunk [KC][NC]
      const float4* Wg = reinterpret_cast<const float4*>(W + (size_t)k0 * NC);
      float4* wl4 = reinterpret_cast<float4*>(wl);
      constexpr int n4 = KC * NC / 4;
#pragma unroll
      for (int i0 = 0; i0 < n4 / 256; ++i0) wl4[t + i0 * 256] = Wg[t + i0 * 256];
    }
    {  // stage x chunk [RB][KC]
      constexpr int n4 = RB * KC / 4;
#pragma unroll
      for (int i0 = 0; i0 < n4 / 256; ++i0) {
        int i = t + i0 * 256;
        int rr = i / (KC / 4);
        int k4 = i % (KC / 4);
        int grow = min(r0 + rr, N - 1);
        float4 v = *reinterpret_cast<const float4*>(&A[(size_t)grow * K + k0 + k4 * 4]);
        xl[rr][k4 * 4 + 0] = v.x;
        xl[rr][k4 * 4 + 1] = v.y;
        xl[rr][k4 * 4 + 2] = v.z;
        xl[rr][k4 * 4 + 3] = v.w;
      }
    }
    __syncthreads();
#pragma unroll 8
    for (int kk = 0; kk < KC; ++kk) {
      const float4* wrow = reinterpret_cast<const float4*>(&wl[kk * NC + c0]);
      float4 w0 = wrow[0], w1 = wrow[1];
      float wv[8] = {w0.x, w0.y, w0.z, w0.w, w1.x, w1.y, w1.z, w1.w};
      float xv[4];
#pragma unroll
      for (int r = 0; r < 4; ++r) xv[r] = xl[ty * 4 + r][kk];
#pragma unroll
      for (int r = 0; r < 4; ++r)
#pragma unroll
        for (int c = 0; c < 8; ++c) acc[r][c] = fmaf(xv[r], wv[c], acc[r][c]);
    }
  }

#pragma unroll
  for (int r = 0; r < 4; ++r) {
    int grow = r0 + ty * 4 + r;
    if (grow < N) {
      float s = dinv[grow];
      float4 o0 = make_float4(acc[r][0] * s, acc[r][1] * s, acc[r][2] * s, acc[r][3] * s);
      float4 o1 = make_float4(acc[r][4] * s, acc[r][5] * s, acc[r][6] * s, acc[r][7] * s);
      float4* op = reinterpret_cast<float4*>(&out[(size_t)grow * NC + c0]);
      op[0] = o0;
      op[1] = o1;
    }
  }
}

// One wave per node; lane owns F/64 dims. Pull-gather over CSR.
template <int F, bool RELU>
__global__ __launch_bounds__(256) void aggregate_kernel(
    const float* __restrict__ hs, const int* __restrict__ offs,
    const int* __restrict__ csr, const float* __restrict__ dinv,
    const float* __restrict__ bias, float* __restrict__ out, int N) {
  int node = blockIdx.x * 4 + (threadIdx.x >> 6);
  if (node >= N) return;  // wave-uniform
  int lane = threadIdx.x & 63;
  int beg = __builtin_amdgcn_readfirstlane(offs[node]);
  int end = __builtin_amdgcn_readfirstlane(offs[node + 1]);
  float scale = dinv[node];
  if constexpr (F == 128) {
    float2 acc = reinterpret_cast<const float2*>(hs + (size_t)node * F)[lane];  // self
    for (int j = beg; j < end; ++j) {
      int r = csr[j];
      float2 v = reinterpret_cast<const float2*>(hs + (size_t)r * F)[lane];
      acc.x += v.x;
      acc.y += v.y;
    }
    float2 b = reinterpret_cast<const float2*>(bias)[lane];
    float ox = fmaf(scale, acc.x, b.x);
    float oy = fmaf(scale, acc.y, b.y);
    if (RELU) {
      ox = fmaxf(ox, 0.f);
      oy = fmaxf(oy, 0.f);
    }
    reinterpret_cast<float2*>(out + (size_t)node * F)[lane] = make_float2(ox, oy);
  } else {
    float acc = hs[(size_t)node * F + lane];  // self
    for (int j = beg; j < end; ++j) {
      int r = csr[j];
      acc += hs[(size_t)r * F + lane];
    }
    float o = fmaf(scale, acc, bias[lane]);
    if (RELU) o = fmaxf(o, 0.f);
    out[(size_t)node * F + lane] = o;
  }
}

extern "C" void kernel_launch(void* const* d_in, const int* in_sizes, int n_in,
                              void* d_out, int out_size, void* d_ws, size_t ws_size,
                              hipStream_t stream) {
  const float* x = (const float*)d_in[0];
  const int* ei = (const int*)d_in[1];   // int32 on device (harness converts)
  const float* W1 = (const float*)d_in[2];
  const float* b1 = (const float*)d_in[3];
  const float* W2 = (const float*)d_in[4];
  const float* b2 = (const float*)d_in[5];
  float* out = (float*)d_out;

  const int IN = 256, HID = 128;
  int N = in_sizes[0] / IN;   // 100000
  int E = in_sizes[1] / 2;    // 1600000

  char* ws = (char*)d_ws;
  size_t off = 0;
  auto alloc = [&](size_t bytes) -> void* {
    void* p = ws + off;
    off += (bytes + 255) & ~(size_t)255;
    return p;
  };
  int* cnt = (int*)alloc((size_t)N * 4);
  int* offs = (int*)alloc(((size_t)N + 1) * 4);
  int* cursor = (int*)alloc((size_t)N * 4);
  float* dinv = (float*)alloc((size_t)N * 4);
  int* bsums = (int*)alloc(1024 * 4);
  int* csr = (int*)alloc((size_t)E * 4);
  float* h1s = (float*)alloc((size_t)N * HID * 4);
  float* a1 = (float*)alloc((size_t)N * HID * 4);
  float* h2s = h1s;  // h1s dead after aggregate1 -> reuse for layer-2 GEMM out

  hipMemsetAsync(cnt, 0, (size_t)N * 4, stream);
  int eb = (E + 255) / 256;
  hist_kernel<<<eb, 256, 0, stream>>>(ei, E, cnt, N);
  int nb = (N + 1023) / 1024;  // 98 <= 256
  scan_partial<<<nb, 256, 0, stream>>>(cnt, offs, bsums, N);
  scan_bsums<<<1, 256, 0, stream>>>(bsums, nb);
  finalize_kernel<<<(N + 255) / 256, 256, 0, stream>>>(cnt, offs, cursor, dinv, bsums, N, E);
  fill_kernel<<<eb, 256, 0, stream>>>(ei, E, cursor, csr, N);

  gemm_scaled<256, 128, 64><<<(N + 63) / 64, 256, 0, stream>>>(x, W1, dinv, h1s, N);
  aggregate_kernel<128, true><<<(N + 3) / 4, 256, 0, stream>>>(h1s, offs, csr, dinv, b1, a1, N);
  gemm_scaled<128, 64, 128><<<(N + 127) / 128, 256, 0, stream>>>(a1, W2, dinv, h2s, N);
  aggregate_kernel<64, false><<<(N + 3) / 4, 256, 0, stream>>>(h2s, offs, csr, dinv, b2, out, N);
}